// Round 1
// baseline (10.454 us; speedup 1.0000x reference)
//
#include <hip/hip_runtime.h>

// Analytic reduction of the 3-qubit circuit:
//   CNOT(0,1) and CNOT(1,2) preserve the b0 index -> commute with Z_0.
//   Qubit 0 state = RY(theta0)*RY(p0)|0> = [cos((p0+t0)/2), sin((p0+t0)/2)]
//   <Z_0> = cos^2 - sin^2 = cos(p0 + theta0).
// So out[i] = cosf(patches[3*i] + theta[0]). Pure memory-bound streaming.

__global__ __launch_bounds__(256) void qconv3_vec4_kernel(
    const float* __restrict__ patches,   // [B,3] flat
    const float* __restrict__ theta,     // [3]
    float* __restrict__ out,             // [B]
    int n4)                              // B/4
{
    int t = blockIdx.x * blockDim.x + threadIdx.x;
    if (t >= n4) return;
    float t0 = theta[0];
    const float4* p = reinterpret_cast<const float4*>(patches) + 3 * (size_t)t;
    float4 v0 = p[0];   // patches[12t+0 .. 12t+3]
    float4 v1 = p[1];   // patches[12t+4 .. 12t+7]
    float4 v2 = p[2];   // patches[12t+8 .. 12t+11]
    float4 o;
    o.x = cosf(v0.x + t0);   // patch 4t+0, elem 0 -> flat 12t+0
    o.y = cosf(v0.w + t0);   // patch 4t+1, elem 0 -> flat 12t+3
    o.z = cosf(v1.z + t0);   // patch 4t+2, elem 0 -> flat 12t+6
    o.w = cosf(v2.y + t0);   // patch 4t+3, elem 0 -> flat 12t+9
    reinterpret_cast<float4*>(out)[t] = o;
}

// Scalar fallback for any tail / non-multiple-of-4 sizes (not expected here).
__global__ __launch_bounds__(256) void qconv3_scalar_kernel(
    const float* __restrict__ patches,
    const float* __restrict__ theta,
    float* __restrict__ out,
    int n, int start)
{
    int i = start + blockIdx.x * blockDim.x + threadIdx.x;
    if (i >= n) return;
    out[i] = cosf(patches[3 * (size_t)i] + theta[0]);
}

extern "C" void kernel_launch(void* const* d_in, const int* in_sizes, int n_in,
                              void* d_out, int out_size, void* d_ws, size_t ws_size,
                              hipStream_t stream) {
    const float* patches = (const float*)d_in[0];
    const float* theta   = (const float*)d_in[1];
    float* out = (float*)d_out;

    int n  = out_size;          // B
    int n4 = n / 4;
    if (n4 > 0) {
        int blocks = (n4 + 255) / 256;
        qconv3_vec4_kernel<<<blocks, 256, 0, stream>>>(patches, theta, out, n4);
    }
    int tail = n - n4 * 4;
    if (tail > 0) {
        qconv3_scalar_kernel<<<1, 256, 0, stream>>>(patches, theta, out, n, n4 * 4);
    }
}